// Round 5
// baseline (269.316 us; speedup 1.0000x reference)
//
#include <hip/hip_runtime.h>
#include <hip/hip_bf16.h>

#define NB 4
#define NC 512
#define NN 4096
#define NM 640
#define LOG2E 1.4426950408889634f

typedef __attribute__((ext_vector_type(8))) short bf16x8;
typedef __attribute__((ext_vector_type(4))) float f32x4;

__device__ __forceinline__ f32x4 mfma16(bf16x8 a, bf16x8 b, f32x4 c) {
  return __builtin_amdgcn_mfma_f32_16x16x32_bf16(a, b, c, 0, 0, 0);
}

__device__ __forceinline__ unsigned short f2bf(float f) {
  unsigned int u = __float_as_uint(f);
  u += 0x7fffu + ((u >> 16) & 1u);   // round-to-nearest-even
  return (unsigned short)(u >> 16);
}

// ---------------- pack weights: W[640][512] bf16 + bias[640] f32 ----------------
__global__ void pack_w(const float* __restrict__ wq, const float* __restrict__ bq,
                       const float* __restrict__ wk, const float* __restrict__ bk,
                       const float* __restrict__ wv, const float* __restrict__ bv,
                       unsigned short* __restrict__ W, float* __restrict__ bias) {
  int idx = blockIdx.x * 256 + threadIdx.x;
  if (idx < NM * NC) {
    int r = idx >> 9, c = idx & (NC - 1);
    float v;
    if (r < 64) v = wq[r * NC + c];
    else if (r < 128) v = wk[(r - 64) * NC + c];
    else v = wv[(r - 128) * NC + c];
    W[idx] = f2bf(v);
  }
  if (idx < NM)
    bias[idx] = (idx < 64) ? bq[idx] : (idx < 128 ? bk[idx - 64] : bv[idx - 128]);
}

// ---------------- transpose + convert: x[b][c][n] f32 -> XT[b][n][c] bf16 ----------------
__global__ void xpose(const float* __restrict__ x, unsigned short* __restrict__ XT) {
  __shared__ float t[64][65];
  int b = blockIdx.z;
  int c0 = blockIdx.y * 64, n0 = blockIdx.x * 64;
  int tx = threadIdx.x & 63, ty = threadIdx.x >> 6;  // 256 threads
  const float* xb = x + (size_t)b * NC * NN;
#pragma unroll
  for (int i = 0; i < 16; ++i) {
    int c = i * 4 + ty;
    t[c][tx] = xb[(size_t)(c0 + c) * NN + n0 + tx];
  }
  __syncthreads();
  unsigned short* xtb = XT + (size_t)b * NN * NC;
#pragma unroll
  for (int i = 0; i < 16; ++i) {
    int n = i * 4 + ty;
    xtb[(size_t)(n0 + n) * NC + c0 + tx] = f2bf(t[tx][n]);
  }
}

// ---------------- QKV projection GEMM (NT): C[m][n] = sum_k W[m][k]*XT[n][k] ----------------
// grid (8, 8, 4) = 256 blocks (balanced, 1/CU), 512 threads. Tile: 80 m x 512 n.
// Q rows are pre-scaled by LOG2E so attention works in exp2 domain.
__global__ __launch_bounds__(512) void gemm_qkv(
    const unsigned short* __restrict__ W, const float* __restrict__ bias,
    const unsigned short* __restrict__ XT,
    unsigned short* __restrict__ QT, unsigned short* __restrict__ KT,
    unsigned short* __restrict__ V) {
  int b = blockIdx.z;
  int m0 = blockIdx.y * 80;
  int wave = threadIdx.x >> 6, lane = threadIdx.x & 63;
  int nw = blockIdx.x * 512 + wave * 64;
  int lcol = lane & 15, lkg = lane >> 4;
  const unsigned short* xtb = XT + (size_t)b * NN * NC;
  f32x4 acc[5][4] = {};
  for (int k0 = 0; k0 < NC; k0 += 32) {
    int ko = k0 + lkg * 8;
    bf16x8 afr[5], bfr[4];
#pragma unroll
    for (int i = 0; i < 5; ++i)
      afr[i] = *reinterpret_cast<const bf16x8*>(W + (size_t)(m0 + 16 * i + lcol) * NC + ko);
#pragma unroll
    for (int j = 0; j < 4; ++j)
      bfr[j] = *reinterpret_cast<const bf16x8*>(xtb + (size_t)(nw + 16 * j + lcol) * NC + ko);
#pragma unroll
    for (int i = 0; i < 5; ++i)
#pragma unroll
      for (int j = 0; j < 4; ++j)
        acc[i][j] = mfma16(afr[i], bfr[j], acc[i][j]);
  }
  int rbase = lkg * 4;  // D row = (lane>>4)*4 + r, col = lane&15
#pragma unroll
  for (int i = 0; i < 5; ++i) {
    int mrow = m0 + 16 * i;  // block-uniform subtile base
    if (mrow < 128) {
      // Q or K subtile -> write transposed [n][64] bf16 (Q pre-scaled by LOG2E)
      bool isq = mrow < 64;
      unsigned short* T = isq ? (QT + (size_t)b * NN * 64) : (KT + (size_t)b * NN * 64);
      int mb = mrow & 63;
      float sc = isq ? LOG2E : 1.0f;
#pragma unroll
      for (int j = 0; j < 4; ++j) {
        int n = nw + 16 * j + lcol;
        union { unsigned short h[4]; unsigned long long u; } pk;
#pragma unroll
        for (int r = 0; r < 4; ++r)
          pk.h[r] = f2bf((acc[i][j][r] + bias[mrow + rbase + r]) * sc);
        *reinterpret_cast<unsigned long long*>(T + (size_t)n * 64 + mb + rbase) = pk.u;
      }
    } else {
      // V subtile -> row-major [c][n] bf16
      unsigned short* vb = V + (size_t)b * NC * NN;
#pragma unroll
      for (int r = 0; r < 4; ++r) {
        int m = mrow + rbase + r;
        float bs = bias[m];
        int c = m - 128;
#pragma unroll
        for (int j = 0; j < 4; ++j) {
          int n = nw + 16 * j + lcol;
          vb[(size_t)c * NN + n] = f2bf(acc[i][j][r] + bs);
        }
      }
    }
  }
}

// ---------------- attention stats: exact m_j, l_j per column (log2 domain) ----------------
// grid 256 = (b, 64-j block) with XCD-pair swizzle. 8 waves stripe i independently.
// NO per-iteration barriers; single merge at the end. Q one-ahead prefetched.
__global__ __launch_bounds__(512) void attn_stats(
    const unsigned short* __restrict__ QT, const unsigned short* __restrict__ KT,
    float* __restrict__ Mst, float* __restrict__ Lst) {
  int bid = blockIdx.x;
  int b = (bid & 7) >> 1;
  int jb = ((bid >> 3) << 1) | (bid & 1);
  int j0 = jb * 64;
  int wave = threadIdx.x >> 6, lane = threadIdx.x & 63;
  int lcol = lane & 15, lkg = lane >> 4;

  __shared__ float sm[64][9], sl[64][9];

  const unsigned short* qt = QT + (size_t)b * NN * 64;
  const unsigned short* kt = KT + (size_t)b * NN * 64;

  bf16x8 kfr[4][2];
#pragma unroll
  for (int fn = 0; fn < 4; ++fn)
#pragma unroll
    for (int ks = 0; ks < 2; ++ks)
      kfr[fn][ks] = *reinterpret_cast<const bf16x8*>(
          kt + (size_t)(j0 + 16 * fn + lcol) * 64 + ks * 32 + lkg * 8);

  float m_l[4], l_l[4];
#pragma unroll
  for (int fn = 0; fn < 4; ++fn) { m_l[fn] = -1e30f; l_l[fn] = 0.f; }

  bf16x8 qfr[2];
#pragma unroll
  for (int ks = 0; ks < 2; ++ks)
    qfr[ks] = *reinterpret_cast<const bf16x8*>(
        qt + (size_t)(wave * 16 + lcol) * 64 + ks * 32 + lkg * 8);

  for (int it = 0; it < NN / 128; ++it) {
    f32x4 s[4] = {};
#pragma unroll
    for (int ks = 0; ks < 2; ++ks)
#pragma unroll
      for (int fn = 0; fn < 4; ++fn)
        s[fn] = mfma16(qfr[ks], kfr[fn][ks], s[fn]);
    // prefetch next Q strip (consumed next iter; latency hides under stats VALU)
    if (it + 1 < NN / 128) {
      int ib = ((it + 1) * 8 + wave) * 16;
#pragma unroll
      for (int ks = 0; ks < 2; ++ks)
        qfr[ks] = *reinterpret_cast<const bf16x8*>(
            qt + (size_t)(ib + lcol) * 64 + ks * 32 + lkg * 8);
    }
#pragma unroll
    for (int fn = 0; fn < 4; ++fn) {
      float mx = fmaxf(fmaxf(s[fn][0], s[fn][1]), fmaxf(s[fn][2], s[fn][3]));
      float nm = fmaxf(m_l[fn], mx);
      float ps = 0.f;
#pragma unroll
      for (int r = 0; r < 4; ++r) ps += exp2f(s[fn][r] - nm);
      l_l[fn] = l_l[fn] * exp2f(m_l[fn] - nm) + ps;
      m_l[fn] = nm;
    }
  }

  // merge the 4 lkg replicas (lanes differing in bits 4,5)
#pragma unroll
  for (int fn = 0; fn < 4; ++fn) {
#pragma unroll
    for (int off = 16; off <= 32; off <<= 1) {
      float om = __shfl_xor(m_l[fn], off), ol = __shfl_xor(l_l[fn], off);
      float nm = fmaxf(m_l[fn], om);
      l_l[fn] = l_l[fn] * exp2f(m_l[fn] - nm) + ol * exp2f(om - nm);
      m_l[fn] = nm;
    }
    if (lkg == 0) { sm[16 * fn + lcol][wave] = m_l[fn]; sl[16 * fn + lcol][wave] = l_l[fn]; }
  }
  __syncthreads();
  if (wave == 0) {
    int j = lane;  // 0..63
    float m = -1e30f, l = 0.f;
#pragma unroll
    for (int w = 0; w < 8; ++w) {
      float om = sm[j][w], ol = sl[j][w];
      float nm = fmaxf(m, om);
      l = l * exp2f(m - nm) + ol * exp2f(om - nm);
      m = nm;
    }
    Mst[(size_t)b * NN + j0 + j] = m;   // log2-domain max
    Lst[(size_t)b * NN + j0 + j] = l;
  }
}

// ---------------- attention PV: pure GEMM pipeline with known (m,l) ----------------
// grid 256 = (b, jb) XCD-swizzled, 8 waves. Wave w owns rows c in [64w, 64w+64).
// One raw barrier per iter. Q/V loads for iter t+1 are issued right after PV(t)
// consumes the buffers (single rotating buffer, FIFO vmcnt keeps V in flight).
__global__ __launch_bounds__(512) void attn_pv(
    const unsigned short* __restrict__ QT, const unsigned short* __restrict__ KT,
    const unsigned short* __restrict__ V, const float* __restrict__ x,
    const float* __restrict__ gamma, const float* __restrict__ Mst,
    const float* __restrict__ Lst, float* __restrict__ out) {
  int bid = blockIdx.x;
  int b = (bid & 7) >> 1;
  int jb = ((bid >> 3) << 1) | (bid & 1);
  int j0 = jb * 64;
  int wave = threadIdx.x >> 6, lane = threadIdx.x & 63;
  int lcol = lane & 15, lkg = lane >> 4;

  __shared__ __align__(16) unsigned short plds[2][64 * 128];  // P^T [j][i] double-buffered

  const unsigned short* qt = QT + (size_t)b * NN * 64;
  const unsigned short* kt = KT + (size_t)b * NN * 64;
  const unsigned short* vp = V + (size_t)b * NC * NN;

  bf16x8 qfr[2];
  bf16x8 vfr[4][4];  // [ks][cm]
  // issue Q FIRST then V: wait-for-Q at QK^T leaves the 16 V loads in flight
  auto issueQV = [&](int it) {
    int i0 = it * 128;
#pragma unroll
    for (int ks = 0; ks < 2; ++ks)
      qfr[ks] = *reinterpret_cast<const bf16x8*>(
          qt + (size_t)(i0 + 16 * wave + lcol) * 64 + ks * 32 + lkg * 8);
#pragma unroll
    for (int ks = 0; ks < 4; ++ks)
#pragma unroll
      for (int cm = 0; cm < 4; ++cm)
        vfr[ks][cm] = *reinterpret_cast<const bf16x8*>(
            vp + (size_t)(64 * wave + 16 * cm + lcol) * NN + i0 + ks * 32 + lkg * 8);
  };

  issueQV(0);

  bf16x8 kfr[4][2];
  float mlog[4], lj[4];
#pragma unroll
  for (int fn = 0; fn < 4; ++fn) {
#pragma unroll
    for (int ks = 0; ks < 2; ++ks)
      kfr[fn][ks] = *reinterpret_cast<const bf16x8*>(
          kt + (size_t)(j0 + 16 * fn + lcol) * 64 + ks * 32 + lkg * 8);
    mlog[fn] = Mst[(size_t)b * NN + j0 + 16 * fn + lcol];  // already log2-domain
    lj[fn] = Lst[(size_t)b * NN + j0 + 16 * fn + lcol];
  }

  f32x4 oacc[4][4] = {};  // [cm][fn]

  for (int it = 0; it < NN / 128; ++it) {
    char* pbuf = reinterpret_cast<char*>(plds[it & 1]);

    // ---- S strip: rows [i0+16*wave, +16) x 64 cols (Q pre-scaled by log2e) ----
    f32x4 s[4] = {};
#pragma unroll
    for (int ks = 0; ks < 2; ++ks)
#pragma unroll
      for (int fn = 0; fn < 4; ++fn)
        s[fn] = mfma16(qfr[ks], kfr[fn][ks], s[fn]);

    // ---- P = exp2(S - m), pack bf16, write P^T swizzled ----
#pragma unroll
    for (int fn = 0; fn < 4; ++fn) {
      union { unsigned short h[4]; unsigned long long u; } pk;
#pragma unroll
      for (int r = 0; r < 4; ++r)
        pk.h[r] = f2bf(exp2f(s[fn][r] - mlog[fn]));
      int j = 16 * fn + lcol;
      int byteoff = (j * 256 + wave * 32 + lkg * 8) ^ ((j & 7) << 4);
      *reinterpret_cast<unsigned long long*>(pbuf + byteoff) = pk.u;
    }

    // ---- raw barrier: drain LDS writes only; V global loads remain in flight ----
    asm volatile("s_waitcnt lgkmcnt(0)" ::: "memory");
    __builtin_amdgcn_s_barrier();
    asm volatile("" ::: "memory");

    // ---- PV: O[64c][64j] += V[c][i-block] * P^T ----
    __builtin_amdgcn_s_setprio(1);
#pragma unroll
    for (int ks = 0; ks < 4; ++ks) {
      bf16x8 pfr[4];
#pragma unroll
      for (int fn = 0; fn < 4; ++fn) {
        int j = 16 * fn + lcol;
        int byteoff = (j * 256 + ks * 64 + lkg * 16) ^ ((j & 7) << 4);
        pfr[fn] = *reinterpret_cast<const bf16x8*>(pbuf + byteoff);
      }
#pragma unroll
      for (int cm = 0; cm < 4; ++cm)
#pragma unroll
        for (int fn = 0; fn < 4; ++fn)
          oacc[cm][fn] = mfma16(vfr[ks][cm], pfr[fn], oacc[cm][fn]);
    }
    __builtin_amdgcn_s_setprio(0);

    // ---- pipeline: issue next iteration's Q+V now (buffers just went dead) ----
    if (it + 1 < NN / 128) issueQV(it + 1);
  }

  // ---- epilogue: out = gamma * O/l + x ----
  float g = gamma[0];
  const float* xb = x + (size_t)b * NC * NN;
  float* ob = out + (size_t)b * NC * NN;
#pragma unroll
  for (int fn = 0; fn < 4; ++fn) {
    float sc = g / lj[fn];
    int j = j0 + 16 * fn + lcol;
#pragma unroll
    for (int cm = 0; cm < 4; ++cm) {
      int c = 64 * wave + 16 * cm + lkg * 4;
#pragma unroll
      for (int r = 0; r < 4; ++r) {
        size_t idx = (size_t)(c + r) * NN + j;
        ob[idx] = oacc[cm][fn][r] * sc + xb[idx];
      }
    }
  }
}

extern "C" void kernel_launch(void* const* d_in, const int* in_sizes, int n_in,
                              void* d_out, int out_size, void* d_ws, size_t ws_size,
                              hipStream_t stream) {
  const float* x  = (const float*)d_in[0];
  const float* wq = (const float*)d_in[1];
  const float* bq = (const float*)d_in[2];
  const float* wk = (const float*)d_in[3];
  const float* bk = (const float*)d_in[4];
  const float* wv = (const float*)d_in[5];
  const float* bv = (const float*)d_in[6];
  const float* gm = (const float*)d_in[7];
  float* out = (float*)d_out;

  char* ws = (char*)d_ws;
  unsigned short* XT = (unsigned short*)(ws);                             // 16 MB
  unsigned short* Vb = (unsigned short*)(ws + (size_t)16 * 1024 * 1024);  // 16 MB
  unsigned short* QT = (unsigned short*)(ws + (size_t)32 * 1024 * 1024);  // 2 MB
  unsigned short* KT = (unsigned short*)(ws + (size_t)34 * 1024 * 1024);  // 2 MB
  unsigned short* Wp = (unsigned short*)(ws + (size_t)36 * 1024 * 1024);  // 640 KB
  float* biasp = (float*)(ws + (size_t)36 * 1024 * 1024 + 704 * 1024);    // 2.5 KB
  float* Mst   = (float*)(ws + (size_t)36 * 1024 * 1024 + 768 * 1024);    // 64 KB
  float* Lst   = (float*)(ws + (size_t)36 * 1024 * 1024 + 832 * 1024);    // 64 KB

  pack_w<<<(NM * NC + 255) / 256, 256, 0, stream>>>(wq, bq, wk, bk, wv, bv, Wp, biasp);
  xpose<<<dim3(NN / 64, NC / 64, NB), 256, 0, stream>>>(x, XT);
  gemm_qkv<<<dim3(NN / 512, NM / 80, NB), 512, 0, stream>>>(Wp, biasp, XT, QT, KT, Vb);
  attn_stats<<<256, 512, 0, stream>>>(QT, KT, Mst, Lst);
  attn_pv<<<256, 512, 0, stream>>>(QT, KT, Vb, x, gm, Mst, Lst, out);
}

// Round 6
// 268.404 us; speedup vs baseline: 1.0034x; 1.0034x over previous
//
#include <hip/hip_runtime.h>
#include <hip/hip_bf16.h>

#define NB 4
#define NC 512
#define NN 4096
#define NM 640
#define LOG2E 1.4426950408889634f

typedef __attribute__((ext_vector_type(8))) short bf16x8;
typedef __attribute__((ext_vector_type(4))) float f32x4;

__device__ __forceinline__ f32x4 mfma16(bf16x8 a, bf16x8 b, f32x4 c) {
  return __builtin_amdgcn_mfma_f32_16x16x32_bf16(a, b, c, 0, 0, 0);
}

__device__ __forceinline__ unsigned short f2bf(float f) {
  unsigned int u = __float_as_uint(f);
  u += 0x7fffu + ((u >> 16) & 1u);   // round-to-nearest-even
  return (unsigned short)(u >> 16);
}

// ---------------- pack weights: W[640][512] bf16 + bias[640] f32 ----------------
__global__ void pack_w(const float* __restrict__ wq, const float* __restrict__ bq,
                       const float* __restrict__ wk, const float* __restrict__ bk,
                       const float* __restrict__ wv, const float* __restrict__ bv,
                       unsigned short* __restrict__ W, float* __restrict__ bias) {
  int idx = blockIdx.x * 256 + threadIdx.x;
  if (idx < NM * NC) {
    int r = idx >> 9, c = idx & (NC - 1);
    float v;
    if (r < 64) v = wq[r * NC + c];
    else if (r < 128) v = wk[(r - 64) * NC + c];
    else v = wv[(r - 128) * NC + c];
    W[idx] = f2bf(v);
  }
  if (idx < NM)
    bias[idx] = (idx < 64) ? bq[idx] : (idx < 128 ? bk[idx - 64] : bv[idx - 128]);
}

// ---------------- transpose + convert: x[b][c][n] f32 -> XT[b][n][c] bf16 ----------------
__global__ void xpose(const float* __restrict__ x, unsigned short* __restrict__ XT) {
  __shared__ float t[64][65];
  int b = blockIdx.z;
  int c0 = blockIdx.y * 64, n0 = blockIdx.x * 64;
  int tx = threadIdx.x & 63, ty = threadIdx.x >> 6;  // 256 threads
  const float* xb = x + (size_t)b * NC * NN;
#pragma unroll
  for (int i = 0; i < 16; ++i) {
    int c = i * 4 + ty;
    t[c][tx] = xb[(size_t)(c0 + c) * NN + n0 + tx];
  }
  __syncthreads();
  unsigned short* xtb = XT + (size_t)b * NN * NC;
#pragma unroll
  for (int i = 0; i < 16; ++i) {
    int n = i * 4 + ty;
    xtb[(size_t)(n0 + n) * NC + c0 + tx] = f2bf(t[tx][n]);
  }
}

// ---------------- QKV projection GEMM (NT): C[m][n] = sum_k W[m][k]*XT[n][k] ----------------
// grid (8, 8, 4) = 256 blocks (balanced, 1/CU), 512 threads. Tile: 80 m x 512 n.
// Q rows are pre-scaled by LOG2E so attention works in exp2 domain.
__global__ __launch_bounds__(512) void gemm_qkv(
    const unsigned short* __restrict__ W, const float* __restrict__ bias,
    const unsigned short* __restrict__ XT,
    unsigned short* __restrict__ QT, unsigned short* __restrict__ KT,
    unsigned short* __restrict__ V) {
  int b = blockIdx.z;
  int m0 = blockIdx.y * 80;
  int wave = threadIdx.x >> 6, lane = threadIdx.x & 63;
  int nw = blockIdx.x * 512 + wave * 64;
  int lcol = lane & 15, lkg = lane >> 4;
  const unsigned short* xtb = XT + (size_t)b * NN * NC;
  f32x4 acc[5][4] = {};
  for (int k0 = 0; k0 < NC; k0 += 32) {
    int ko = k0 + lkg * 8;
    bf16x8 afr[5], bfr[4];
#pragma unroll
    for (int i = 0; i < 5; ++i)
      afr[i] = *reinterpret_cast<const bf16x8*>(W + (size_t)(m0 + 16 * i + lcol) * NC + ko);
#pragma unroll
    for (int j = 0; j < 4; ++j)
      bfr[j] = *reinterpret_cast<const bf16x8*>(xtb + (size_t)(nw + 16 * j + lcol) * NC + ko);
#pragma unroll
    for (int i = 0; i < 5; ++i)
#pragma unroll
      for (int j = 0; j < 4; ++j)
        acc[i][j] = mfma16(afr[i], bfr[j], acc[i][j]);
  }
  int rbase = lkg * 4;  // D row = (lane>>4)*4 + r, col = lane&15
#pragma unroll
  for (int i = 0; i < 5; ++i) {
    int mrow = m0 + 16 * i;  // block-uniform subtile base
    if (mrow < 128) {
      // Q or K subtile -> write transposed [n][64] bf16 (Q pre-scaled by LOG2E)
      bool isq = mrow < 64;
      unsigned short* T = isq ? (QT + (size_t)b * NN * 64) : (KT + (size_t)b * NN * 64);
      int mb = mrow & 63;
      float sc = isq ? LOG2E : 1.0f;
#pragma unroll
      for (int j = 0; j < 4; ++j) {
        int n = nw + 16 * j + lcol;
        union { unsigned short h[4]; unsigned long long u; } pk;
#pragma unroll
        for (int r = 0; r < 4; ++r)
          pk.h[r] = f2bf((acc[i][j][r] + bias[mrow + rbase + r]) * sc);
        *reinterpret_cast<unsigned long long*>(T + (size_t)n * 64 + mb + rbase) = pk.u;
      }
    } else {
      // V subtile -> row-major [c][n] bf16
      unsigned short* vb = V + (size_t)b * NC * NN;
#pragma unroll
      for (int r = 0; r < 4; ++r) {
        int m = mrow + rbase + r;
        float bs = bias[m];
        int c = m - 128;
#pragma unroll
        for (int j = 0; j < 4; ++j) {
          int n = nw + 16 * j + lcol;
          vb[(size_t)c * NN + n] = f2bf(acc[i][j][r] + bs);
        }
      }
    }
  }
}

// ---------------- attention stats: exact m_j, l_j per column (log2 domain) ----------------
__global__ __launch_bounds__(512, 2) void attn_stats(
    const unsigned short* __restrict__ QT, const unsigned short* __restrict__ KT,
    float* __restrict__ Mst, float* __restrict__ Lst) {
  int bid = blockIdx.x;
  int b = (bid & 7) >> 1;
  int jb = ((bid >> 3) << 1) | (bid & 1);
  int j0 = jb * 64;
  int wave = threadIdx.x >> 6, lane = threadIdx.x & 63;
  int lcol = lane & 15, lkg = lane >> 4;

  __shared__ float sm[64][9], sl[64][9];

  const unsigned short* qt = QT + (size_t)b * NN * 64;
  const unsigned short* kt = KT + (size_t)b * NN * 64;

  bf16x8 kfr[4][2];
#pragma unroll
  for (int fn = 0; fn < 4; ++fn)
#pragma unroll
    for (int ks = 0; ks < 2; ++ks)
      kfr[fn][ks] = *reinterpret_cast<const bf16x8*>(
          kt + (size_t)(j0 + 16 * fn + lcol) * 64 + ks * 32 + lkg * 8);

  float m_l[4], l_l[4];
#pragma unroll
  for (int fn = 0; fn < 4; ++fn) { m_l[fn] = -1e30f; l_l[fn] = 0.f; }

  bf16x8 qfr[2];
#pragma unroll
  for (int ks = 0; ks < 2; ++ks)
    qfr[ks] = *reinterpret_cast<const bf16x8*>(
        qt + (size_t)(wave * 16 + lcol) * 64 + ks * 32 + lkg * 8);

  for (int it = 0; it < NN / 128; ++it) {
    f32x4 s[4] = {};
#pragma unroll
    for (int ks = 0; ks < 2; ++ks)
#pragma unroll
      for (int fn = 0; fn < 4; ++fn)
        s[fn] = mfma16(qfr[ks], kfr[fn][ks], s[fn]);
    // prefetch next Q strip (consumed next iter; latency hides under stats VALU)
    if (it + 1 < NN / 128) {
      int ib = ((it + 1) * 8 + wave) * 16;
#pragma unroll
      for (int ks = 0; ks < 2; ++ks)
        qfr[ks] = *reinterpret_cast<const bf16x8*>(
            qt + (size_t)(ib + lcol) * 64 + ks * 32 + lkg * 8);
    }
#pragma unroll
    for (int fn = 0; fn < 4; ++fn) {
      float mx = fmaxf(fmaxf(s[fn][0], s[fn][1]), fmaxf(s[fn][2], s[fn][3]));
      float nm = fmaxf(m_l[fn], mx);
      float ps = 0.f;
#pragma unroll
      for (int r = 0; r < 4; ++r) ps += exp2f(s[fn][r] - nm);
      l_l[fn] = l_l[fn] * exp2f(m_l[fn] - nm) + ps;
      m_l[fn] = nm;
    }
  }

  // merge the 4 lkg replicas (lanes differing in bits 4,5)
#pragma unroll
  for (int fn = 0; fn < 4; ++fn) {
#pragma unroll
    for (int off = 16; off <= 32; off <<= 1) {
      float om = __shfl_xor(m_l[fn], off), ol = __shfl_xor(l_l[fn], off);
      float nm = fmaxf(m_l[fn], om);
      l_l[fn] = l_l[fn] * exp2f(m_l[fn] - nm) + ol * exp2f(om - nm);
      m_l[fn] = nm;
    }
    if (lkg == 0) { sm[16 * fn + lcol][wave] = m_l[fn]; sl[16 * fn + lcol][wave] = l_l[fn]; }
  }
  __syncthreads();
  if (wave == 0) {
    int j = lane;  // 0..63
    float m = -1e30f, l = 0.f;
#pragma unroll
    for (int w = 0; w < 8; ++w) {
      float om = sm[j][w], ol = sl[j][w];
      float nm = fmaxf(m, om);
      l = l * exp2f(m - nm) + ol * exp2f(om - nm);
      m = nm;
    }
    Mst[(size_t)b * NN + j0 + j] = m;   // log2-domain max
    Lst[(size_t)b * NN + j0 + j] = l;
  }
}

// ---------------- attention PV: pure GEMM pipeline with known (m,l) ----------------
// grid 256 = (b, jb) XCD-swizzled, 8 waves (= 2 waves/SIMD -> 256 VGPR budget).
// One raw barrier per iter. Q/V for iter t+1 issued after PV(t); V fragments pinned
// in registers after the barrier so loads stay hoisted (not sunk into MFMA loop).
__global__ __launch_bounds__(512, 2) void attn_pv(
    const unsigned short* __restrict__ QT, const unsigned short* __restrict__ KT,
    const unsigned short* __restrict__ V, const float* __restrict__ x,
    const float* __restrict__ gamma, const float* __restrict__ Mst,
    const float* __restrict__ Lst, float* __restrict__ out) {
  int bid = blockIdx.x;
  int b = (bid & 7) >> 1;
  int jb = ((bid >> 3) << 1) | (bid & 1);
  int j0 = jb * 64;
  int wave = threadIdx.x >> 6, lane = threadIdx.x & 63;
  int lcol = lane & 15, lkg = lane >> 4;

  __shared__ __align__(16) unsigned short plds[2][64 * 128];  // P^T [j][i] double-buffered

  const unsigned short* qt = QT + (size_t)b * NN * 64;
  const unsigned short* kt = KT + (size_t)b * NN * 64;
  const unsigned short* vp = V + (size_t)b * NC * NN;

  bf16x8 qfr[2];
  bf16x8 vfr[4][4];  // [ks][cm]
  // issue Q FIRST then V: wait-for-Q at QK^T leaves the 16 V loads in flight
  auto issueQV = [&](int it) {
    int i0 = it * 128;
#pragma unroll
    for (int ks = 0; ks < 2; ++ks)
      qfr[ks] = *reinterpret_cast<const bf16x8*>(
          qt + (size_t)(i0 + 16 * wave + lcol) * 64 + ks * 32 + lkg * 8);
#pragma unroll
    for (int ks = 0; ks < 4; ++ks)
#pragma unroll
      for (int cm = 0; cm < 4; ++cm)
        vfr[ks][cm] = *reinterpret_cast<const bf16x8*>(
            vp + (size_t)(64 * wave + 16 * cm + lcol) * NN + i0 + ks * 32 + lkg * 8);
  };

  issueQV(0);

  bf16x8 kfr[4][2];
  float mlog[4], lj[4];
#pragma unroll
  for (int fn = 0; fn < 4; ++fn) {
#pragma unroll
    for (int ks = 0; ks < 2; ++ks)
      kfr[fn][ks] = *reinterpret_cast<const bf16x8*>(
          kt + (size_t)(j0 + 16 * fn + lcol) * 64 + ks * 32 + lkg * 8);
    mlog[fn] = Mst[(size_t)b * NN + j0 + 16 * fn + lcol];  // already log2-domain
    lj[fn] = Lst[(size_t)b * NN + j0 + 16 * fn + lcol];
  }

  f32x4 oacc[4][4] = {};  // [cm][fn]

  for (int it = 0; it < NN / 128; ++it) {
    char* pbuf = reinterpret_cast<char*>(plds[it & 1]);

    // ---- S strip: rows [i0+16*wave, +16) x 64 cols (Q pre-scaled by log2e) ----
    f32x4 s[4] = {};
#pragma unroll
    for (int ks = 0; ks < 2; ++ks)
#pragma unroll
      for (int fn = 0; fn < 4; ++fn)
        s[fn] = mfma16(qfr[ks], kfr[fn][ks], s[fn]);

    // ---- P = exp2(S - m), pack bf16, write P^T swizzled ----
#pragma unroll
    for (int fn = 0; fn < 4; ++fn) {
      union { unsigned short h[4]; unsigned long long u; } pk;
#pragma unroll
      for (int r = 0; r < 4; ++r)
        pk.h[r] = f2bf(exp2f(s[fn][r] - mlog[fn]));
      int j = 16 * fn + lcol;
      int byteoff = (j * 256 + wave * 32 + lkg * 8) ^ ((j & 7) << 4);
      *reinterpret_cast<unsigned long long*>(pbuf + byteoff) = pk.u;
    }

    // ---- raw barrier: drain LDS writes only; V global loads remain in flight ----
    asm volatile("s_waitcnt lgkmcnt(0)" ::: "memory");
    __builtin_amdgcn_s_barrier();
    asm volatile("" ::: "memory");

    // ---- pin V fragments: force materialization as registers HERE (vmcnt wait
    //      lands here, one full iteration after issue -> hidden) ----
#pragma unroll
    for (int ks = 0; ks < 4; ++ks)
#pragma unroll
      for (int cm = 0; cm < 4; ++cm)
        asm volatile("" : "+v"(vfr[ks][cm]));

    // ---- PV: O[64c][64j] += V[c][i-block] * P^T ----
    __builtin_amdgcn_s_setprio(1);
#pragma unroll
    for (int ks = 0; ks < 4; ++ks) {
      bf16x8 pfr[4];
#pragma unroll
      for (int fn = 0; fn < 4; ++fn) {
        int j = 16 * fn + lcol;
        int byteoff = (j * 256 + ks * 64 + lkg * 16) ^ ((j & 7) << 4);
        pfr[fn] = *reinterpret_cast<const bf16x8*>(pbuf + byteoff);
      }
#pragma unroll
      for (int cm = 0; cm < 4; ++cm)
#pragma unroll
        for (int fn = 0; fn < 4; ++fn)
          oacc[cm][fn] = mfma16(vfr[ks][cm], pfr[fn], oacc[cm][fn]);
    }
    __builtin_amdgcn_s_setprio(0);

    // ---- pipeline: issue next iteration's Q+V now (buffers just went dead) ----
    if (it + 1 < NN / 128) {
      issueQV(it + 1);
      __builtin_amdgcn_sched_barrier(0);  // keep the issue point here
    }
  }

  // ---- epilogue: out = gamma * O/l + x ----
  float g = gamma[0];
  const float* xb = x + (size_t)b * NC * NN;
  float* ob = out + (size_t)b * NC * NN;
#pragma unroll
  for (int fn = 0; fn < 4; ++fn) {
    float sc = g / lj[fn];
    int j = j0 + 16 * fn + lcol;
#pragma unroll
    for (int cm = 0; cm < 4; ++cm) {
      int c = 64 * wave + 16 * cm + lkg * 4;
#pragma unroll
      for (int r = 0; r < 4; ++r) {
        size_t idx = (size_t)(c + r) * NN + j;
        ob[idx] = oacc[cm][fn][r] * sc + xb[idx];
      }
    }
  }
}

extern "C" void kernel_launch(void* const* d_in, const int* in_sizes, int n_in,
                              void* d_out, int out_size, void* d_ws, size_t ws_size,
                              hipStream_t stream) {
  const float* x  = (const float*)d_in[0];
  const float* wq = (const float*)d_in[1];
  const float* bq = (const float*)d_in[2];
  const float* wk = (const float*)d_in[3];
  const float* bk = (const float*)d_in[4];
  const float* wv = (const float*)d_in[5];
  const float* bv = (const float*)d_in[6];
  const float* gm = (const float*)d_in[7];
  float* out = (float*)d_out;

  char* ws = (char*)d_ws;
  unsigned short* XT = (unsigned short*)(ws);                             // 16 MB
  unsigned short* Vb = (unsigned short*)(ws + (size_t)16 * 1024 * 1024);  // 16 MB
  unsigned short* QT = (unsigned short*)(ws + (size_t)32 * 1024 * 1024);  // 2 MB
  unsigned short* KT = (unsigned short*)(ws + (size_t)34 * 1024 * 1024);  // 2 MB
  unsigned short* Wp = (unsigned short*)(ws + (size_t)36 * 1024 * 1024);  // 640 KB
  float* biasp = (float*)(ws + (size_t)36 * 1024 * 1024 + 704 * 1024);    // 2.5 KB
  float* Mst   = (float*)(ws + (size_t)36 * 1024 * 1024 + 768 * 1024);    // 64 KB
  float* Lst   = (float*)(ws + (size_t)36 * 1024 * 1024 + 832 * 1024);    // 64 KB

  pack_w<<<(NM * NC + 255) / 256, 256, 0, stream>>>(wq, bq, wk, bk, wv, bv, Wp, biasp);
  xpose<<<dim3(NN / 64, NC / 64, NB), 256, 0, stream>>>(x, XT);
  gemm_qkv<<<dim3(NN / 512, NM / 80, NB), 512, 0, stream>>>(Wp, biasp, XT, QT, KT, Vb);
  attn_stats<<<256, 512, 0, stream>>>(QT, KT, Mst, Lst);
  attn_pv<<<256, 512, 0, stream>>>(QT, KT, Vb, x, gm, Mst, Lst, out);
}